// Round 17
// baseline (1161.661 us; speedup 1.0000x reference)
//
#include <hip/hip_runtime.h>

#define Bn   32
#define Cn   64
#define Ln   4096
#define Nn   (Bn*Cn*Ln)      // 8388608
#define FLn  8
#define MIDn 16
#define TILE3 64
#define NTD  64              // ODE outputs per block (double-step tile rows = 96)

typedef __bf16 bf16_t;
typedef bf16_t bf16x4 __attribute__((ext_vector_type(4)));
typedef bf16_t bf16x8 __attribute__((ext_vector_type(8)));
typedef float  f32x4  __attribute__((ext_vector_type(4)));

__device__ __forceinline__ float tanh_fast(float x) {
    float t = __expf(2.0f * x);
    return 1.0f - __fdividef(2.0f, 1.0f + t);
}
__device__ __forceinline__ float gelu_fast(float x) {
    return __fdividef(x, 1.0f + __expf(-1.702f * x));
}
__device__ __forceinline__ float sigmoid_f(float x) {
    return 1.0f / (1.0f + __expf(-x));
}

// ---------------- weight prep: MFMA A-frags (16x16x32) ----------------
__global__ __launch_bounds__(256) void prep_weights(
    const float* __restrict__ w1, const float* __restrict__ w2,
    const float* __restrict__ gw, const float* __restrict__ aw1,
    const float* __restrict__ aw2,
    bf16_t* __restrict__ w1f, bf16_t* __restrict__ w2f,
    bf16_t* __restrict__ gwf, bf16_t* __restrict__ aw1f,
    float* __restrict__ aw2t)
{
    int idx = blockIdx.x*256 + threadIdx.x;
    if (idx < 1536) {
        int lane = idx & 63;
        int f  = (idx >> 6) % 6;
        int mt = (idx >> 6) / 6;
        int tau = f >> 1, kc = f & 1;
        int oc = mt*16 + (lane & 15);
        int c0 = kc*32 + (lane >> 4)*8;
        #pragma unroll
        for (int e = 0; e < 8; ++e) {
            int c = c0 + e;
            w1f[idx*8 + e] = (bf16_t)w1[oc*192 + c*3 + tau];
            w2f[idx*8 + e] = (bf16_t)w2[oc*192 + c*3 + tau];
        }
    }
    if (idx < 4608) {
        int lane = idx & 63;
        int r  = idx >> 6;
        int f  = r % 6;
        int mt = (r / 6) % 4;
        int lvl = r / 24;
        int tau = f >> 1, kc = f & 1;
        int oc = mt*16 + (lane & 15);
        int c0 = kc*32 + (lane >> 4)*8;
        #pragma unroll
        for (int e = 0; e < 8; ++e)
            gwf[idx*8 + e] = (bf16_t)gw[((lvl*64 + oc)*64 + (c0+e))*3 + tau];
    }
    if (idx < 256) {
        int lane = idx & 63;
        int kc  = (idx >> 6) & 1;
        int lvl = idx >> 7;
        int mm = lane & 15;
        int c0 = kc*32 + (lane >> 4)*8;
        #pragma unroll
        for (int e = 0; e < 8; ++e)
            aw1f[idx*8 + e] = (bf16_t)aw1[lvl*1024 + mm*64 + c0 + e];
    }
    if (idx < 2*64*16) {
        int lvl = idx / 1024, rem = idx % 1024;
        int oc = rem / 16, mm = rem % 16;
        aw2t[lvl*1024 + mm*64 + oc] = aw2[idx];
    }
}

// ---------------- fused DOUBLE RK4-step kernel (v12) ----------------
// Two RK4 steps per dispatch; fp32 carry in LDS Z0F (conflict-swizzled,
// 4-float granule). Optional fused per-row output sums -> msum (last step).
__global__ __launch_bounds__(256, 2) void ode_rk4_2step(
    const float* __restrict__ zsrc, float* __restrict__ zdst,
    const bf16_t* __restrict__ w1f, const float* __restrict__ b1,
    const bf16_t* __restrict__ w2f, const float* __restrict__ b2,
    const float* __restrict__ damp_p, float* __restrict__ msum)
{
    __shared__ bf16_t ZC[96*64];     // 12288 B  current state (bf16)
    __shared__ bf16_t HT[96*64];     // 12288 B  h = gelu(conv1(state))
    __shared__ float  Z0F[96*64];    // 24576 B  step-begin state (fp32, swz4)
    __shared__ bf16_t SUMB[80*64];   // 10240 B  k1 + 2k2 + 2k3 (bf16), rows p-8

    const int tid  = threadIdx.x;
    const int w    = tid >> 6;
    const int lane = tid & 63;
    const int c15  = lane & 15;
    const int hb   = lane >> 4;
    const int oc0  = w*16 + hb*4;
    const int b    = blockIdx.y;
    const int l0   = blockIdx.x * NTD;
    const size_t bbase = (size_t)b * Cn * Ln;
    const float damp = damp_p[0];
    const int pmin = (blockIdx.x == 0) ? 16 : 0;
    const int pmax = (blockIdx.x == gridDim.x - 1) ? 79 : 95;

    // ---- stage zsrc -> ZC (bf16) and Z0F (fp32, 4-float-granule swizzle) ----
    #pragma unroll
    for (int jj = 0; jj < 4; ++jj) {
        const int cc0 = (w << 4) + jj*4;
        const float* zr0 = zsrc + bbase + (size_t)(cc0+0) * Ln;
        const float* zr1 = zsrc + bbase + (size_t)(cc0+1) * Ln;
        const float* zr2 = zsrc + bbase + (size_t)(cc0+2) * Ln;
        const float* zr3 = zsrc + bbase + (size_t)(cc0+3) * Ln;
        #pragma unroll
        for (int m2 = 0; m2 < 2; ++m2) {
            int p = lane + (m2 << 6);
            if (p < 96) {
                int l = l0 - 16 + p;
                l = l < 0 ? 0 : (l > Ln-1 ? Ln-1 : l);
                f32x4 vf;
                vf[0] = zr0[l]; vf[1] = zr1[l];
                vf[2] = zr2[l]; vf[3] = zr3[l];
                bf16x4 vb;
                #pragma unroll
                for (int e = 0; e < 4; ++e) vb[e] = (bf16_t)vf[e];
                *(bf16x4*)&ZC[p*64 + (cc0 ^ ((p & 7) << 3))] = vb;
                *(f32x4*)&Z0F[p*64 + (cc0 ^ ((p & 7) << 2))] = vf;
            }
        }
    }

    f32x4 bias1v, bias2v;
    #pragma unroll
    for (int j = 0; j < 4; ++j) {
        bias1v[j] = b1[oc0 + j];
        bias2v[j] = b2[oc0 + j];
    }
    bf16x8 af1[6], af2[6];
    {
        const bf16x8* wp1 = (const bf16x8*)w1f + (w*6)*64 + lane;
        const bf16x8* wp2 = (const bf16x8*)w2f + (w*6)*64 + lane;
        #pragma unroll
        for (int f = 0; f < 6; ++f) { af1[f] = wp1[f*64]; af2[f] = wp2[f*64]; }
    }

    f32x4 osum = (f32x4)0.0f;      // fused output row-sum partials

    __syncthreads();

    for (int i = 0; i < 8; ++i) {
        const int hLo = 2*i + 1, hHi = 95 - 2*i;
        const int kLo = 2*i + 2, kHi = 94 - 2*i;
        const int ii  = i & 3;

        // ---- phase A: conv1 -> gelu -> HT (6 units/wave) ----
        #pragma unroll
        for (int nt = 0; nt < 6; ++nt) {
            int ph = nt*16 + c15;
            f32x4 acc = bias1v;
            #pragma unroll
            for (int tau = 0; tau < 3; ++tau) {
                int p = ph + tau - 1;
                p = p < pmin ? pmin : (p > pmax ? pmax : p);
                int base = p*64 + ((hb*8) ^ ((p & 7) << 3));
                acc = __builtin_amdgcn_mfma_f32_16x16x32_bf16(
                    af1[tau*2+0], *(const bf16x8*)&ZC[base], acc, 0, 0, 0);
                acc = __builtin_amdgcn_mfma_f32_16x16x32_bf16(
                    af1[tau*2+1], *(const bf16x8*)&ZC[base ^ 32], acc, 0, 0, 0);
            }
            if (ph >= hLo && ph < hHi) {
                bf16x4 hv;
                #pragma unroll
                for (int j = 0; j < 4; ++j)
                    hv[j] = (bf16_t)gelu_fast(acc[j]);
                *(bf16x4*)&HT[ph*64 + (oc0 ^ ((ph & 7) << 3))] = hv;
            }
        }
        __syncthreads();

        // ---- phase B: conv2 -> tanh -> k -> state update / combine ----
        #pragma unroll
        for (int nt = 0; nt < 6; ++nt) {
            int pk = nt*16 + c15;
            f32x4 acc = bias2v;
            #pragma unroll
            for (int tau = 0; tau < 3; ++tau) {
                int q = pk + tau - 1;
                q = q < pmin ? pmin : (q > pmax ? pmax : q);
                int base = q*64 + ((hb*8) ^ ((q & 7) << 3));
                acc = __builtin_amdgcn_mfma_f32_16x16x32_bf16(
                    af2[tau*2+0], *(const bf16x8*)&HT[base], acc, 0, 0, 0);
                acc = __builtin_amdgcn_mfma_f32_16x16x32_bf16(
                    af2[tau*2+1], *(const bf16x8*)&HT[base ^ 32], acc, 0, 0, 0);
            }
            if (pk >= kLo && pk < kHi) {
                const int col  = oc0 ^ ((pk & 7) << 3);
                const int off  = pk*64 + col;
                const int offF = pk*64 + (oc0 ^ ((pk & 7) << 2));
                const int soff = (pk-8)*64 + col;       // k regions ⊂ [8,88)
                bf16x4 zc = *(const bf16x4*)&ZC[off];
                f32x4  z0 = *(const f32x4*)&Z0F[offF];
                if (ii < 3) {
                    const float alpha = (ii == 2) ? 0.10f : 0.05f;
                    bf16x4 sv;
                    if (ii > 0) sv = *(const bf16x4*)&SUMB[soff];
                    bf16x4 wv, nsv;
                    #pragma unroll
                    for (int j = 0; j < 4; ++j) {
                        float kv = tanh_fast(acc[j]) - damp * (float)zc[j];
                        wv[j]  = (bf16_t)(z0[j] + alpha * kv);
                        nsv[j] = (ii == 0) ? (bf16_t)kv
                                           : (bf16_t)((float)sv[j] + 2.0f * kv);
                    }
                    *(bf16x4*)&ZC[off] = wv;
                    *(bf16x4*)&SUMB[soff] = nsv;
                } else {
                    bf16x4 sv = *(const bf16x4*)&SUMB[soff];
                    if (i == 3) {
                        f32x4 z1; bf16x4 zb;
                        #pragma unroll
                        for (int j = 0; j < 4; ++j) {
                            float kv = tanh_fast(acc[j]) - damp * (float)zc[j];
                            z1[j] = z0[j] + (0.1f/6.0f) * ((float)sv[j] + kv);
                            zb[j] = (bf16_t)z1[j];
                        }
                        *(f32x4*)&Z0F[offF] = z1;
                        *(bf16x4*)&ZC[off] = zb;
                    } else {                  // i == 7: final output (+ row sums)
                        int gcol = l0 + pk - 16;
                        #pragma unroll
                        for (int j = 0; j < 4; ++j) {
                            float kv = tanh_fast(acc[j]) - damp * (float)zc[j];
                            float ov = z0[j] + (0.1f/6.0f) * ((float)sv[j] + kv);
                            size_t gof = bbase + (size_t)(oc0 + j)*Ln + gcol;
                            zdst[gof] = ov;
                            osum[j] += ov;
                        }
                    }
                }
            }
        }
        if (i < 7) __syncthreads();
    }

    // fused per-row sums of the output (only when msum != nullptr)
    if (msum) {
        #pragma unroll
        for (int j = 0; j < 4; ++j) {
            float s = osum[j];
            s += __shfl_xor(s, 1, 64);
            s += __shfl_xor(s, 2, 64);
            s += __shfl_xor(s, 4, 64);
            s += __shfl_xor(s, 8, 64);
            if (c15 == 0) atomicAdd(&msum[b*64 + oc0 + j], s);
        }
    }
}

// ---------------- dywan: tiny MLP -> lo/hi + ortho (input = row sums) ---------
__global__ __launch_bounds__(256) void dywan_kernel(
    const float* __restrict__ m,
    const float* __restrict__ stat_w, const float* __restrict__ stat_b,
    const float* __restrict__ gen1_w, const float* __restrict__ gen1_b,
    const float* __restrict__ gen2_w, const float* __restrict__ gen2_b,
    float* __restrict__ tail, int lvl)
{
    __shared__ float m_s[Bn][Cn];
    __shared__ float stat_s[Bn][64];
    __shared__ float g1_s[Bn][128];
    __shared__ float g_s[Bn][16];
    __shared__ float ored[Bn];
    const int tid = threadIdx.x;
    for (int i = tid; i < Bn*Cn; i += 256) m_s[i>>6][i&63] = m[i] * (1.0f/Ln);
    __syncthreads();
    for (int i = tid; i < Bn*64; i += 256) {
        int b = i >> 6, h = i & 63;
        float a = stat_b[h];
        for (int c = 0; c < Cn; ++c) a = fmaf(stat_w[h*64+c], m_s[b][c], a);
        stat_s[b][h] = 0.5f * a * (1.0f + erff(a * 0.7071067811865476f));
    }
    __syncthreads();
    for (int i = tid; i < Bn*128; i += 256) {
        int b = i >> 7, j = i & 127;
        float a = gen1_b[j];
        for (int h = 0; h < 64; ++h) a = fmaf(gen1_w[j*64+h], stat_s[b][h], a);
        g1_s[b][j] = 0.5f * a * (1.0f + erff(a * 0.7071067811865476f));
    }
    __syncthreads();
    for (int i = tid; i < Bn*16; i += 256) {
        int b = i >> 4, q = i & 15;
        float a = gen2_b[q];
        for (int j = 0; j < 128; ++j) a = fmaf(gen2_w[q*128+j], g1_s[b][j], a);
        g_s[b][q] = a;
    }
    __syncthreads();
    for (int i = tid; i < Bn*16; i += 256) {
        int b = i >> 4, q = i & 15;
        if (q < FLn) tail[1 + lvl*(Bn*FLn) + b*FLn + q] = g_s[b][q];
        else         tail[1 + 3*(Bn*FLn) + lvl*(Bn*FLn) + b*FLn + (q-FLn)] = g_s[b][q];
    }
    if (tid < Bn) {
        const int b = tid;
        float S1 = 0.f, n2 = 0.f, sm = 0.f, prev = 0.f;
        #pragma unroll
        for (int k = 0; k < FLn; ++k) {
            float v = g_s[b][k];
            S1 += fabsf(v); n2 = fmaf(v, v, n2);
            sm += fabsf(v - prev); prev = v;
        }
        sm += fabsf(prev);
        float den = sqrtf(n2) + 1e-8f;
        float Sn = S1 / den;
        float s2n = n2 / (den*den);
        ored[b] = 0.01f * (3.0f*Sn*Sn*(1.0f/2048.0f) + fabsf(s2n - 1.0f)*(1.0f/32.0f))
                + 0.1f * sm * (1.0f/288.0f);
    }
    __syncthreads();
    if (tid == 0) {
        float o = 0.f;
        for (int b = 0; b < Bn; ++b) o += ored[b];
        if (lvl == 0) tail[0] = o; else tail[0] += o;
    }
}

// ---------------- per-batch 8-tap FIR + fused next-level row-sum ----------------
__global__ __launch_bounds__(256) void filter_kernel(
    const float* __restrict__ in, float* __restrict__ napprox,
    float* __restrict__ det,
    const float* __restrict__ lo, const float* __restrict__ hi,
    float* __restrict__ msum)
{
    const int bc = blockIdx.y;
    const int b = bc >> 6;
    float lov[8], hiv[8];
    #pragma unroll
    for (int k = 0; k < 8; ++k) { lov[k] = lo[b*8+k]; hiv[k] = hi[b*8+k]; }
    const float* __restrict__ row = in + (size_t)bc*Ln;
    const int l = blockIdx.x*256 + threadIdx.x;
    float na = 0.0f, dv = 0.0f;
    #pragma unroll
    for (int k = 0; k < 8; ++k) {
        int j = l + k - 4;
        j = j < 0 ? 0 : (j >= Ln ? Ln-1 : j);
        float v = row[j];
        na = fmaf(v, lov[k], na);
        dv = fmaf(v, hiv[k], dv);
    }
    size_t g = (size_t)bc*Ln + l;
    if (napprox) napprox[g] = na;
    det[g] = dv;
    if (msum) {
        float s = na;
        #pragma unroll
        for (int off = 32; off > 0; off >>= 1) s += __shfl_down(s, off, 64);
        __shared__ float red[4];
        if ((threadIdx.x & 63) == 0) red[threadIdx.x >> 6] = s;
        __syncthreads();
        if (threadIdx.x == 0)
            atomicAdd(&msum[bc], red[0]+red[1]+red[2]+red[3]);
    }
}

// ---------------- reconstruction: MFMA gate conv + MFMA att1 ----------------
template<bool HAS_ATT>
__global__ __launch_bounds__(256, 2) void stage3_kernel(
    const float* __restrict__ cur_in, float* __restrict__ det,
    float* __restrict__ cur_out,
    const bf16_t* __restrict__ gwf, const float* __restrict__ gb,
    const bf16_t* __restrict__ aw1f, const float* __restrict__ ab1,
    const float* __restrict__ aw2t, const float* __restrict__ ab2)
{
    __shared__ bf16_t CB[66*64];
    __shared__ float t1_s[16][65];
    __shared__ float gate_s[64][65];
    __shared__ float att_s[64][65];

    const int tid  = threadIdx.x;
    const int w    = tid >> 6;
    const int lane = tid & 63;
    const int c15  = lane & 15;
    const int hb   = lane >> 4;
    const int oc0  = w*16 + hb*4;
    const int b    = blockIdx.y;
    const int l0   = blockIdx.x * TILE3;
    const size_t bbase = (size_t)b * Cn * Ln;

    #pragma unroll
    for (int jj = 0; jj < 4; ++jj) {
        const int cc0 = (w << 4) + jj*4;
        const float* cr0 = cur_in + bbase + (size_t)(cc0+0) * Ln;
        const float* cr1 = cur_in + bbase + (size_t)(cc0+1) * Ln;
        const float* cr2 = cur_in + bbase + (size_t)(cc0+2) * Ln;
        const float* cr3 = cur_in + bbase + (size_t)(cc0+3) * Ln;
        #pragma unroll
        for (int m2 = 0; m2 < 2; ++m2) {
            int p = lane + (m2 << 6);
            if (p < 66) {
                int l = l0 - 1 + p;
                bool in = (l >= 0) && (l < Ln);
                bf16x4 v;
                v[0] = (bf16_t)(in ? cr0[l] : 0.0f);
                v[1] = (bf16_t)(in ? cr1[l] : 0.0f);
                v[2] = (bf16_t)(in ? cr2[l] : 0.0f);
                v[3] = (bf16_t)(in ? cr3[l] : 0.0f);
                *(bf16x4*)&CB[p*64 + (cc0 ^ ((p & 7) << 3))] = v;
            }
        }
    }
    __syncthreads();

    if (HAS_ATT) {
        f32x4 acc;
        #pragma unroll
        for (int j = 0; j < 4; ++j) acc[j] = ab1[hb*4 + j];
        const int p = w*16 + c15 + 1;
        #pragma unroll
        for (int kc = 0; kc < 2; ++kc) {
            bf16x8 a1 = ((const bf16x8*)aw1f)[kc*64 + lane];
            int base = p*64 + (((kc*32) + hb*8) ^ ((p & 7) << 3));
            acc = __builtin_amdgcn_mfma_f32_16x16x32_bf16(
                a1, *(const bf16x8*)&CB[base], acc, 0, 0, 0);
        }
        #pragma unroll
        for (int j = 0; j < 4; ++j)
            t1_s[hb*4 + j][w*16 + c15] = gelu_fast(acc[j]);
    }

    {
        bf16x8 ag[6];
        const bf16x8* wp = (const bf16x8*)gwf + (w*6)*64 + lane;
        #pragma unroll
        for (int f = 0; f < 6; ++f) ag[f] = wp[f*64];
        f32x4 biasg;
        #pragma unroll
        for (int j = 0; j < 4; ++j) biasg[j] = gb[oc0 + j];

        #pragma unroll
        for (int nt = 0; nt < 5; ++nt) {
            int ph = nt*16 + c15;
            f32x4 acc = biasg;
            #pragma unroll
            for (int tau = 0; tau < 3; ++tau) {
                int q = ph - 1 + tau;
                q = q < 0 ? 0 : (q > 65 ? 65 : q);
                int base0 = q*64 + ((hb*8) ^ ((q & 7) << 3));
                acc = __builtin_amdgcn_mfma_f32_16x16x32_bf16(
                    ag[tau*2+0], *(const bf16x8*)&CB[base0], acc, 0, 0, 0);
                acc = __builtin_amdgcn_mfma_f32_16x16x32_bf16(
                    ag[tau*2+1], *(const bf16x8*)&CB[base0 ^ 32], acc, 0, 0, 0);
            }
            if (ph >= 1 && ph < 65) {
                int t = ph - 1;
                #pragma unroll
                for (int j = 0; j < 4; ++j)
                    gate_s[oc0 + j][t] = sigmoid_f(acc[j]);
            }
        }
    }
    __syncthreads();

    if (HAS_ATT) {
        const int oc = tid & 63;
        const int t0 = (tid >> 6) * 16;
        float w2r[16];
        #pragma unroll
        for (int mm = 0; mm < MIDn; ++mm) w2r[mm] = aw2t[mm*64 + oc];
        float av[16];
        const float bb = ab2[oc];
        #pragma unroll
        for (int j = 0; j < 16; ++j) av[j] = bb;
        #pragma unroll
        for (int mm = 0; mm < MIDn; ++mm) {
            #pragma unroll
            for (int j = 0; j < 16; ++j) av[j] = fmaf(w2r[mm], t1_s[mm][t0+j], av[j]);
        }
        #pragma unroll
        for (int j = 0; j < 16; ++j) att_s[oc][t0+j] = sigmoid_f(av[j]);
        __syncthreads();
    }

    const size_t gb0 = bbase + l0;
    for (int e = tid; e < Cn*TILE3; e += 256) {
        int c = e >> 6, t = e & 63;
        size_t g = gb0 + (size_t)c*Ln + t;
        float d = det[g];
        if (HAS_ATT) { d = d * (1.0f + att_s[c][t]); det[g] = d; }
        cur_out[g] = cur_in[g] + gate_s[c][t]*d;
    }
}

extern "C" void kernel_launch(void* const* d_in, const int* in_sizes, int n_in,
                              void* d_out, int out_size, void* d_ws, size_t ws_size,
                              hipStream_t stream)
{
    const float* x      = (const float*)d_in[0];
    const float* c1w    = (const float*)d_in[1];
    const float* c1b    = (const float*)d_in[2];
    const float* c2w    = (const float*)d_in[3];
    const float* c2b    = (const float*)d_in[4];
    const float* damp   = (const float*)d_in[5];
    const float* stat_w = (const float*)d_in[6];
    const float* stat_b = (const float*)d_in[7];
    const float* gen1_w = (const float*)d_in[8];
    const float* gen1_b = (const float*)d_in[9];
    const float* gen2_w = (const float*)d_in[10];
    const float* gen2_b = (const float*)d_in[11];
    const float* gate_w = (const float*)d_in[12];
    const float* gate_b = (const float*)d_in[13];
    const float* att_w1 = (const float*)d_in[14];
    const float* att_b1 = (const float*)d_in[15];
    const float* att_w2 = (const float*)d_in[16];
    const float* att_b2 = (const float*)d_in[17];

    float* out = (float*)d_out;
    // workspace: [Z Nn][WSB Nn][aw2t 2048][m0 2048][m1 2048][m2 2048][bf16 weights]
    float* Z    = (float*)d_ws;
    float* WSB  = Z + Nn;
    float* aw2t = WSB + Nn;
    float* m0   = aw2t + 2048;
    float* m1   = m0 + 2048;
    float* m2   = m1 + 2048;
    bf16_t* w1f  = (bf16_t*)(m2 + 2048);
    bf16_t* w2f  = w1f + 12288;
    bf16_t* gwf  = w2f + 12288;
    bf16_t* aw1f = gwf + 36864;

    float* tail = out + (size_t)4*Nn;

    prep_weights<<<144, 256, 0, stream>>>(c1w, c2w, gate_w, att_w1, att_w2,
                                          w1f, w2f, gwf, aw1f, aw2t);
    hipMemsetAsync(m0, 0, 3*2048*sizeof(float), stream);   // zero m0,m1,m2 each call

    // ODE: 5 double-RK4-steps (fp32 carry via LDS Z0F). Chain:
    // x -> WSB -> Z -> WSB -> Z -> WSB  (x_evolved in WSB; last fuses m0 sums)
    dim3 gOde(Ln/NTD, Bn);
    ode_rk4_2step<<<gOde, 256, 0, stream>>>(x,   WSB, w1f, c1b, w2f, c2b, damp, nullptr);
    ode_rk4_2step<<<gOde, 256, 0, stream>>>(WSB, Z,   w1f, c1b, w2f, c2b, damp, nullptr);
    ode_rk4_2step<<<gOde, 256, 0, stream>>>(Z,   WSB, w1f, c1b, w2f, c2b, damp, nullptr);
    ode_rk4_2step<<<gOde, 256, 0, stream>>>(WSB, Z,   w1f, c1b, w2f, c2b, damp, nullptr);
    ode_rk4_2step<<<gOde, 256, 0, stream>>>(Z,   WSB, w1f, c1b, w2f, c2b, damp, m0);

    // stage 2: wavelet levels. approx chain: WSB -> Z -> out0 -> (dropped)
    dim3 gFil(Ln/256, Bn*Cn);
    const float* appr_in[3]  = {WSB, Z, out};
    float*       appr_out[3] = {Z, out, nullptr};
    float*       msum[3]     = {m1, m2, nullptr};
    float*       muse[3]     = {m0, m1, m2};
    for (int lvl = 0; lvl < 3; ++lvl) {
        dywan_kernel<<<1, 256, 0, stream>>>(muse[lvl], stat_w, stat_b, gen1_w, gen1_b,
                                            gen2_w, gen2_b, tail, lvl);
        filter_kernel<<<gFil, 256, 0, stream>>>(appr_in[lvl], appr_out[lvl],
            out + (size_t)(1+lvl)*Nn,
            tail + 1 + lvl*(Bn*FLn),
            tail + 1 + 3*(Bn*FLn) + lvl*(Bn*FLn),
            msum[lvl]);
    }

    // stage 3: reconstruction. cur chain: WSB -> Z -> WSB -> out0 (final)
    dim3 gS3(Ln/TILE3, Bn);
    stage3_kernel<false><<<gS3, 256, 0, stream>>>(WSB, out + (size_t)3*Nn, Z,
        gwf + 2*12288, gate_b + 2*64, nullptr, nullptr, nullptr, nullptr);
    stage3_kernel<true><<<gS3, 256, 0, stream>>>(Z, out + (size_t)2*Nn, WSB,
        gwf + 1*12288, gate_b + 1*64, aw1f + 1024, att_b1 + 16, aw2t + 1024, att_b2 + 64);
    stage3_kernel<true><<<gS3, 256, 0, stream>>>(WSB, out + (size_t)1*Nn, out,
        gwf, gate_b, aw1f, att_b1, aw2t, att_b2);
}

// Round 18
// 1149.781 us; speedup vs baseline: 1.0103x; 1.0103x over previous
//
#include <hip/hip_runtime.h>

#define Bn   32
#define Cn   64
#define Ln   4096
#define Nn   (Bn*Cn*Ln)      // 8388608
#define FLn  8
#define MIDn 16
#define TILE3 64
#define NTD  64              // ODE outputs per block (double-step tile rows = 96)

typedef __bf16 bf16_t;
typedef bf16_t bf16x4 __attribute__((ext_vector_type(4)));
typedef bf16_t bf16x8 __attribute__((ext_vector_type(8)));
typedef float  f32x4  __attribute__((ext_vector_type(4)));

__device__ __forceinline__ float tanh_fast(float x) {
    float t = __expf(2.0f * x);
    return 1.0f - __fdividef(2.0f, 1.0f + t);
}
__device__ __forceinline__ float gelu_fast(float x) {
    return __fdividef(x, 1.0f + __expf(-1.702f * x));
}
__device__ __forceinline__ float sigmoid_f(float x) {
    return 1.0f / (1.0f + __expf(-x));
}

// ---------------- weight prep: MFMA A-frags (16x16x32) ----------------
__global__ __launch_bounds__(256) void prep_weights(
    const float* __restrict__ w1, const float* __restrict__ w2,
    const float* __restrict__ gw, const float* __restrict__ aw1,
    const float* __restrict__ aw2,
    bf16_t* __restrict__ w1f, bf16_t* __restrict__ w2f,
    bf16_t* __restrict__ gwf, bf16_t* __restrict__ aw1f,
    float* __restrict__ aw2t)
{
    int idx = blockIdx.x*256 + threadIdx.x;
    if (idx < 1536) {
        int lane = idx & 63;
        int f  = (idx >> 6) % 6;
        int mt = (idx >> 6) / 6;
        int tau = f >> 1, kc = f & 1;
        int oc = mt*16 + (lane & 15);
        int c0 = kc*32 + (lane >> 4)*8;
        #pragma unroll
        for (int e = 0; e < 8; ++e) {
            int c = c0 + e;
            w1f[idx*8 + e] = (bf16_t)w1[oc*192 + c*3 + tau];
            w2f[idx*8 + e] = (bf16_t)w2[oc*192 + c*3 + tau];
        }
    }
    if (idx < 4608) {
        int lane = idx & 63;
        int r  = idx >> 6;
        int f  = r % 6;
        int mt = (r / 6) % 4;
        int lvl = r / 24;
        int tau = f >> 1, kc = f & 1;
        int oc = mt*16 + (lane & 15);
        int c0 = kc*32 + (lane >> 4)*8;
        #pragma unroll
        for (int e = 0; e < 8; ++e)
            gwf[idx*8 + e] = (bf16_t)gw[((lvl*64 + oc)*64 + (c0+e))*3 + tau];
    }
    if (idx < 256) {
        int lane = idx & 63;
        int kc  = (idx >> 6) & 1;
        int lvl = idx >> 7;
        int mm = lane & 15;
        int c0 = kc*32 + (lane >> 4)*8;
        #pragma unroll
        for (int e = 0; e < 8; ++e)
            aw1f[idx*8 + e] = (bf16_t)aw1[lvl*1024 + mm*64 + c0 + e];
    }
    if (idx < 2*64*16) {
        int lvl = idx / 1024, rem = idx % 1024;
        int oc = rem / 16, mm = rem % 16;
        aw2t[lvl*1024 + mm*64 + oc] = aw2[idx];
    }
}

// ---------------- double-RK4-step core (templated on boundary clamping) -------
// Eval i = 0..7 (ii = i&3): h region [2i+1,95-2i), k region [2i+2,94-2i).
// SUMB accesses guarded to rows [8,88) (all reads at ii==3 lie inside;
// accumulation over those rows is complete at every eval). fp32 carry in Z0F.
template<bool CLAMP>
__device__ __forceinline__ void ode2_core(
    bf16_t* __restrict__ ZC, bf16_t* __restrict__ HT,
    float* __restrict__ Z0F, bf16_t* __restrict__ SUMB,
    const bf16x8* __restrict__ af1, const bf16x8* __restrict__ af2,
    f32x4 bias1v, f32x4 bias2v, float damp,
    int c15, int hb, int oc0, int pmin, int pmax,
    const float* __restrict__ zsrc, float* __restrict__ zdst,
    size_t bbase, int l0, f32x4& osum)
{
    for (int i = 0; i < 8; ++i) {
        const int hLo = 2*i + 1, hHi = 95 - 2*i;
        const int kLo = 2*i + 2, kHi = 94 - 2*i;
        const int ii  = i & 3;

        // ---- phase A: conv1 -> gelu -> HT (6 units/wave) ----
        #pragma unroll
        for (int nt = 0; nt < 6; ++nt) {
            int ph = nt*16 + c15;
            f32x4 acc = bias1v;
            #pragma unroll
            for (int tau = 0; tau < 3; ++tau) {
                int p = ph + tau - 1;
                if (CLAMP) p = p < pmin ? pmin : (p > pmax ? pmax : p);
                int base = p*64 + ((hb*8) ^ ((p & 7) << 3));
                acc = __builtin_amdgcn_mfma_f32_16x16x32_bf16(
                    af1[tau*2+0], *(const bf16x8*)&ZC[base], acc, 0, 0, 0);
                acc = __builtin_amdgcn_mfma_f32_16x16x32_bf16(
                    af1[tau*2+1], *(const bf16x8*)&ZC[base ^ 32], acc, 0, 0, 0);
            }
            if (ph >= hLo && ph < hHi) {
                bf16x4 hv;
                #pragma unroll
                for (int j = 0; j < 4; ++j)
                    hv[j] = (bf16_t)gelu_fast(acc[j]);
                *(bf16x4*)&HT[ph*64 + (oc0 ^ ((ph & 7) << 3))] = hv;
            }
        }
        __syncthreads();

        // ---- phase B: conv2 -> tanh -> k -> state update / combine ----
        #pragma unroll
        for (int nt = 0; nt < 6; ++nt) {
            int pk = nt*16 + c15;
            f32x4 acc = bias2v;
            #pragma unroll
            for (int tau = 0; tau < 3; ++tau) {
                int q = pk + tau - 1;
                if (CLAMP) q = q < pmin ? pmin : (q > pmax ? pmax : q);
                int base = q*64 + ((hb*8) ^ ((q & 7) << 3));
                acc = __builtin_amdgcn_mfma_f32_16x16x32_bf16(
                    af2[tau*2+0], *(const bf16x8*)&HT[base], acc, 0, 0, 0);
                acc = __builtin_amdgcn_mfma_f32_16x16x32_bf16(
                    af2[tau*2+1], *(const bf16x8*)&HT[base ^ 32], acc, 0, 0, 0);
            }
            if (pk >= kLo && pk < kHi) {
                const int col  = oc0 ^ ((pk & 7) << 3);
                const int off  = pk*64 + col;
                const int offF = pk*64 + (oc0 ^ ((pk & 7) << 2));
                const int soff = (pk-8)*64 + col;
                bf16x4 zc = *(const bf16x4*)&ZC[off];
                f32x4  z0 = *(const f32x4*)&Z0F[offF];
                if (ii < 3) {
                    const float alpha = (ii == 2) ? 0.10f : 0.05f;
                    const bool inS = (pk >= 8) && (pk < 88);   // SUMB valid rows
                    bf16x4 sv;
                    if (ii > 0 && inS) sv = *(const bf16x4*)&SUMB[soff];
                    bf16x4 wv, nsv;
                    #pragma unroll
                    for (int j = 0; j < 4; ++j) {
                        float kv = tanh_fast(acc[j]) - damp * (float)zc[j];
                        wv[j]  = (bf16_t)(z0[j] + alpha * kv);
                        nsv[j] = (ii == 0) ? (bf16_t)kv
                                           : (bf16_t)((float)sv[j] + 2.0f * kv);
                    }
                    *(bf16x4*)&ZC[off] = wv;
                    if (inS) *(bf16x4*)&SUMB[soff] = nsv;
                } else {
                    bf16x4 sv = *(const bf16x4*)&SUMB[soff];  // regions ⊆ [8,88)
                    if (i == 3) {
                        f32x4 z1; bf16x4 zb;
                        #pragma unroll
                        for (int j = 0; j < 4; ++j) {
                            float kv = tanh_fast(acc[j]) - damp * (float)zc[j];
                            z1[j] = z0[j] + (0.1f/6.0f) * ((float)sv[j] + kv);
                            zb[j] = (bf16_t)z1[j];
                        }
                        *(f32x4*)&Z0F[offF] = z1;
                        *(bf16x4*)&ZC[off] = zb;
                    } else {                  // i == 7: final output (+ row sums)
                        int gcol = l0 + pk - 16;
                        #pragma unroll
                        for (int j = 0; j < 4; ++j) {
                            float kv = tanh_fast(acc[j]) - damp * (float)zc[j];
                            float ov = z0[j] + (0.1f/6.0f) * ((float)sv[j] + kv);
                            size_t gof = bbase + (size_t)(oc0 + j)*Ln + gcol;
                            zdst[gof] = ov;
                            osum[j] += ov;
                        }
                    }
                }
            }
        }
        if (i < 7) __syncthreads();
    }
}

// ---------------- fused DOUBLE RK4-step kernel (v13) ----------------
__global__ __launch_bounds__(256, 2) void ode_rk4_2step(
    const float* __restrict__ zsrc, float* __restrict__ zdst,
    const bf16_t* __restrict__ w1f, const float* __restrict__ b1,
    const bf16_t* __restrict__ w2f, const float* __restrict__ b2,
    const float* __restrict__ damp_p, float* __restrict__ msum)
{
    __shared__ bf16_t ZC[96*64];     // 12288 B  current state (bf16)
    __shared__ bf16_t HT[96*64];     // 12288 B  h = gelu(conv1(state))
    __shared__ float  Z0F[96*64];    // 24576 B  step-begin state (fp32, swz4)
    __shared__ bf16_t SUMB[80*64];   // 10240 B  k1 + 2k2 + 2k3 (bf16), rows p-8

    const int tid  = threadIdx.x;
    const int w    = tid >> 6;
    const int lane = tid & 63;
    const int c15  = lane & 15;
    const int hb   = lane >> 4;
    const int oc0  = w*16 + hb*4;
    const int b    = blockIdx.y;
    const int l0   = blockIdx.x * NTD;
    const size_t bbase = (size_t)b * Cn * Ln;
    const float damp = damp_p[0];
    const bool edge = (blockIdx.x == 0) || (blockIdx.x == gridDim.x - 1);
    const int pmin = (blockIdx.x == 0) ? 16 : 0;
    const int pmax = (blockIdx.x == gridDim.x - 1) ? 79 : 95;

    // ---- stage zsrc -> ZC (bf16) and Z0F (fp32, 4-float-granule swizzle) ----
    #pragma unroll
    for (int jj = 0; jj < 4; ++jj) {
        const int cc0 = (w << 4) + jj*4;
        const float* zr0 = zsrc + bbase + (size_t)(cc0+0) * Ln;
        const float* zr1 = zsrc + bbase + (size_t)(cc0+1) * Ln;
        const float* zr2 = zsrc + bbase + (size_t)(cc0+2) * Ln;
        const float* zr3 = zsrc + bbase + (size_t)(cc0+3) * Ln;
        #pragma unroll
        for (int m2 = 0; m2 < 2; ++m2) {
            int p = lane + (m2 << 6);
            if (p < 96) {
                int l = l0 - 16 + p;
                if (edge) l = l < 0 ? 0 : (l > Ln-1 ? Ln-1 : l);
                f32x4 vf;
                vf[0] = zr0[l]; vf[1] = zr1[l];
                vf[2] = zr2[l]; vf[3] = zr3[l];
                bf16x4 vb;
                #pragma unroll
                for (int e = 0; e < 4; ++e) vb[e] = (bf16_t)vf[e];
                *(bf16x4*)&ZC[p*64 + (cc0 ^ ((p & 7) << 3))] = vb;
                *(f32x4*)&Z0F[p*64 + (cc0 ^ ((p & 7) << 2))] = vf;
            }
        }
    }

    f32x4 bias1v, bias2v;
    #pragma unroll
    for (int j = 0; j < 4; ++j) {
        bias1v[j] = b1[oc0 + j];
        bias2v[j] = b2[oc0 + j];
    }
    bf16x8 af1[6], af2[6];
    {
        const bf16x8* wp1 = (const bf16x8*)w1f + (w*6)*64 + lane;
        const bf16x8* wp2 = (const bf16x8*)w2f + (w*6)*64 + lane;
        #pragma unroll
        for (int f = 0; f < 6; ++f) { af1[f] = wp1[f*64]; af2[f] = wp2[f*64]; }
    }

    f32x4 osum = (f32x4)0.0f;

    __syncthreads();

    if (edge)
        ode2_core<true >(ZC, HT, Z0F, SUMB, af1, af2, bias1v, bias2v, damp,
                         c15, hb, oc0, pmin, pmax, zsrc, zdst, bbase, l0, osum);
    else
        ode2_core<false>(ZC, HT, Z0F, SUMB, af1, af2, bias1v, bias2v, damp,
                         c15, hb, oc0, pmin, pmax, zsrc, zdst, bbase, l0, osum);

    // fused per-row sums of the output (only when msum != nullptr)
    if (msum) {
        #pragma unroll
        for (int j = 0; j < 4; ++j) {
            float s = osum[j];
            s += __shfl_xor(s, 1, 64);
            s += __shfl_xor(s, 2, 64);
            s += __shfl_xor(s, 4, 64);
            s += __shfl_xor(s, 8, 64);
            if (c15 == 0) atomicAdd(&msum[b*64 + oc0 + j], s);
        }
    }
}

// ---------------- dywan: tiny MLP -> lo/hi + ortho (input = row sums) ---------
__global__ __launch_bounds__(256) void dywan_kernel(
    const float* __restrict__ m,
    const float* __restrict__ stat_w, const float* __restrict__ stat_b,
    const float* __restrict__ gen1_w, const float* __restrict__ gen1_b,
    const float* __restrict__ gen2_w, const float* __restrict__ gen2_b,
    float* __restrict__ tail, int lvl)
{
    __shared__ float m_s[Bn][Cn];
    __shared__ float stat_s[Bn][64];
    __shared__ float g1_s[Bn][128];
    __shared__ float g_s[Bn][16];
    __shared__ float ored[Bn];
    const int tid = threadIdx.x;
    for (int i = tid; i < Bn*Cn; i += 256) m_s[i>>6][i&63] = m[i] * (1.0f/Ln);
    __syncthreads();
    for (int i = tid; i < Bn*64; i += 256) {
        int b = i >> 6, h = i & 63;
        float a = stat_b[h];
        for (int c = 0; c < Cn; ++c) a = fmaf(stat_w[h*64+c], m_s[b][c], a);
        stat_s[b][h] = 0.5f * a * (1.0f + erff(a * 0.7071067811865476f));
    }
    __syncthreads();
    for (int i = tid; i < Bn*128; i += 256) {
        int b = i >> 7, j = i & 127;
        float a = gen1_b[j];
        for (int h = 0; h < 64; ++h) a = fmaf(gen1_w[j*64+h], stat_s[b][h], a);
        g1_s[b][j] = 0.5f * a * (1.0f + erff(a * 0.7071067811865476f));
    }
    __syncthreads();
    for (int i = tid; i < Bn*16; i += 256) {
        int b = i >> 4, q = i & 15;
        float a = gen2_b[q];
        for (int j = 0; j < 128; ++j) a = fmaf(gen2_w[q*128+j], g1_s[b][j], a);
        g_s[b][q] = a;
    }
    __syncthreads();
    for (int i = tid; i < Bn*16; i += 256) {
        int b = i >> 4, q = i & 15;
        if (q < FLn) tail[1 + lvl*(Bn*FLn) + b*FLn + q] = g_s[b][q];
        else         tail[1 + 3*(Bn*FLn) + lvl*(Bn*FLn) + b*FLn + (q-FLn)] = g_s[b][q];
    }
    if (tid < Bn) {
        const int b = tid;
        float S1 = 0.f, n2 = 0.f, sm = 0.f, prev = 0.f;
        #pragma unroll
        for (int k = 0; k < FLn; ++k) {
            float v = g_s[b][k];
            S1 += fabsf(v); n2 = fmaf(v, v, n2);
            sm += fabsf(v - prev); prev = v;
        }
        sm += fabsf(prev);
        float den = sqrtf(n2) + 1e-8f;
        float Sn = S1 / den;
        float s2n = n2 / (den*den);
        ored[b] = 0.01f * (3.0f*Sn*Sn*(1.0f/2048.0f) + fabsf(s2n - 1.0f)*(1.0f/32.0f))
                + 0.1f * sm * (1.0f/288.0f);
    }
    __syncthreads();
    if (tid == 0) {
        float o = 0.f;
        for (int b = 0; b < Bn; ++b) o += ored[b];
        if (lvl == 0) tail[0] = o; else tail[0] += o;
    }
}

// ---------------- per-batch 8-tap FIR + fused next-level row-sum ----------------
__global__ __launch_bounds__(256) void filter_kernel(
    const float* __restrict__ in, float* __restrict__ napprox,
    float* __restrict__ det,
    const float* __restrict__ lo, const float* __restrict__ hi,
    float* __restrict__ msum)
{
    const int bc = blockIdx.y;
    const int b = bc >> 6;
    float lov[8], hiv[8];
    #pragma unroll
    for (int k = 0; k < 8; ++k) { lov[k] = lo[b*8+k]; hiv[k] = hi[b*8+k]; }
    const float* __restrict__ row = in + (size_t)bc*Ln;
    const int l = blockIdx.x*256 + threadIdx.x;
    float na = 0.0f, dv = 0.0f;
    #pragma unroll
    for (int k = 0; k < 8; ++k) {
        int j = l + k - 4;
        j = j < 0 ? 0 : (j >= Ln ? Ln-1 : j);
        float v = row[j];
        na = fmaf(v, lov[k], na);
        dv = fmaf(v, hiv[k], dv);
    }
    size_t g = (size_t)bc*Ln + l;
    if (napprox) napprox[g] = na;
    det[g] = dv;
    if (msum) {
        float s = na;
        #pragma unroll
        for (int off = 32; off > 0; off >>= 1) s += __shfl_down(s, off, 64);
        __shared__ float red[4];
        if ((threadIdx.x & 63) == 0) red[threadIdx.x >> 6] = s;
        __syncthreads();
        if (threadIdx.x == 0)
            atomicAdd(&msum[bc], red[0]+red[1]+red[2]+red[3]);
    }
}

// ---------------- reconstruction: MFMA gate conv + MFMA att1 ----------------
template<bool HAS_ATT>
__global__ __launch_bounds__(256, 2) void stage3_kernel(
    const float* __restrict__ cur_in, float* __restrict__ det,
    float* __restrict__ cur_out,
    const bf16_t* __restrict__ gwf, const float* __restrict__ gb,
    const bf16_t* __restrict__ aw1f, const float* __restrict__ ab1,
    const float* __restrict__ aw2t, const float* __restrict__ ab2)
{
    __shared__ bf16_t CB[66*64];
    __shared__ float t1_s[16][65];
    __shared__ float gate_s[64][65];
    __shared__ float att_s[64][65];

    const int tid  = threadIdx.x;
    const int w    = tid >> 6;
    const int lane = tid & 63;
    const int c15  = lane & 15;
    const int hb   = lane >> 4;
    const int oc0  = w*16 + hb*4;
    const int b    = blockIdx.y;
    const int l0   = blockIdx.x * TILE3;
    const size_t bbase = (size_t)b * Cn * Ln;

    #pragma unroll
    for (int jj = 0; jj < 4; ++jj) {
        const int cc0 = (w << 4) + jj*4;
        const float* cr0 = cur_in + bbase + (size_t)(cc0+0) * Ln;
        const float* cr1 = cur_in + bbase + (size_t)(cc0+1) * Ln;
        const float* cr2 = cur_in + bbase + (size_t)(cc0+2) * Ln;
        const float* cr3 = cur_in + bbase + (size_t)(cc0+3) * Ln;
        #pragma unroll
        for (int m2 = 0; m2 < 2; ++m2) {
            int p = lane + (m2 << 6);
            if (p < 66) {
                int l = l0 - 1 + p;
                bool in = (l >= 0) && (l < Ln);
                bf16x4 v;
                v[0] = (bf16_t)(in ? cr0[l] : 0.0f);
                v[1] = (bf16_t)(in ? cr1[l] : 0.0f);
                v[2] = (bf16_t)(in ? cr2[l] : 0.0f);
                v[3] = (bf16_t)(in ? cr3[l] : 0.0f);
                *(bf16x4*)&CB[p*64 + (cc0 ^ ((p & 7) << 3))] = v;
            }
        }
    }
    __syncthreads();

    if (HAS_ATT) {
        f32x4 acc;
        #pragma unroll
        for (int j = 0; j < 4; ++j) acc[j] = ab1[hb*4 + j];
        const int p = w*16 + c15 + 1;
        #pragma unroll
        for (int kc = 0; kc < 2; ++kc) {
            bf16x8 a1 = ((const bf16x8*)aw1f)[kc*64 + lane];
            int base = p*64 + (((kc*32) + hb*8) ^ ((p & 7) << 3));
            acc = __builtin_amdgcn_mfma_f32_16x16x32_bf16(
                a1, *(const bf16x8*)&CB[base], acc, 0, 0, 0);
        }
        #pragma unroll
        for (int j = 0; j < 4; ++j)
            t1_s[hb*4 + j][w*16 + c15] = gelu_fast(acc[j]);
    }

    {
        bf16x8 ag[6];
        const bf16x8* wp = (const bf16x8*)gwf + (w*6)*64 + lane;
        #pragma unroll
        for (int f = 0; f < 6; ++f) ag[f] = wp[f*64];
        f32x4 biasg;
        #pragma unroll
        for (int j = 0; j < 4; ++j) biasg[j] = gb[oc0 + j];

        #pragma unroll
        for (int nt = 0; nt < 5; ++nt) {
            int ph = nt*16 + c15;
            f32x4 acc = biasg;
            #pragma unroll
            for (int tau = 0; tau < 3; ++tau) {
                int q = ph - 1 + tau;
                q = q < 0 ? 0 : (q > 65 ? 65 : q);
                int base0 = q*64 + ((hb*8) ^ ((q & 7) << 3));
                acc = __builtin_amdgcn_mfma_f32_16x16x32_bf16(
                    ag[tau*2+0], *(const bf16x8*)&CB[base0], acc, 0, 0, 0);
                acc = __builtin_amdgcn_mfma_f32_16x16x32_bf16(
                    ag[tau*2+1], *(const bf16x8*)&CB[base0 ^ 32], acc, 0, 0, 0);
            }
            if (ph >= 1 && ph < 65) {
                int t = ph - 1;
                #pragma unroll
                for (int j = 0; j < 4; ++j)
                    gate_s[oc0 + j][t] = sigmoid_f(acc[j]);
            }
        }
    }
    __syncthreads();

    if (HAS_ATT) {
        const int oc = tid & 63;
        const int t0 = (tid >> 6) * 16;
        float w2r[16];
        #pragma unroll
        for (int mm = 0; mm < MIDn; ++mm) w2r[mm] = aw2t[mm*64 + oc];
        float av[16];
        const float bb = ab2[oc];
        #pragma unroll
        for (int j = 0; j < 16; ++j) av[j] = bb;
        #pragma unroll
        for (int mm = 0; mm < MIDn; ++mm) {
            #pragma unroll
            for (int j = 0; j < 16; ++j) av[j] = fmaf(w2r[mm], t1_s[mm][t0+j], av[j]);
        }
        #pragma unroll
        for (int j = 0; j < 16; ++j) att_s[oc][t0+j] = sigmoid_f(av[j]);
        __syncthreads();
    }

    const size_t gb0 = bbase + l0;
    for (int e = tid; e < Cn*TILE3; e += 256) {
        int c = e >> 6, t = e & 63;
        size_t g = gb0 + (size_t)c*Ln + t;
        float d = det[g];
        if (HAS_ATT) { d = d * (1.0f + att_s[c][t]); det[g] = d; }
        cur_out[g] = cur_in[g] + gate_s[c][t]*d;
    }
}

extern "C" void kernel_launch(void* const* d_in, const int* in_sizes, int n_in,
                              void* d_out, int out_size, void* d_ws, size_t ws_size,
                              hipStream_t stream)
{
    const float* x      = (const float*)d_in[0];
    const float* c1w    = (const float*)d_in[1];
    const float* c1b    = (const float*)d_in[2];
    const float* c2w    = (const float*)d_in[3];
    const float* c2b    = (const float*)d_in[4];
    const float* damp   = (const float*)d_in[5];
    const float* stat_w = (const float*)d_in[6];
    const float* stat_b = (const float*)d_in[7];
    const float* gen1_w = (const float*)d_in[8];
    const float* gen1_b = (const float*)d_in[9];
    const float* gen2_w = (const float*)d_in[10];
    const float* gen2_b = (const float*)d_in[11];
    const float* gate_w = (const float*)d_in[12];
    const float* gate_b = (const float*)d_in[13];
    const float* att_w1 = (const float*)d_in[14];
    const float* att_b1 = (const float*)d_in[15];
    const float* att_w2 = (const float*)d_in[16];
    const float* att_b2 = (const float*)d_in[17];

    float* out = (float*)d_out;
    float* Z    = (float*)d_ws;
    float* WSB  = Z + Nn;
    float* aw2t = WSB + Nn;
    float* m0   = aw2t + 2048;
    float* m1   = m0 + 2048;
    float* m2   = m1 + 2048;
    bf16_t* w1f  = (bf16_t*)(m2 + 2048);
    bf16_t* w2f  = w1f + 12288;
    bf16_t* gwf  = w2f + 12288;
    bf16_t* aw1f = gwf + 36864;

    float* tail = out + (size_t)4*Nn;

    prep_weights<<<144, 256, 0, stream>>>(c1w, c2w, gate_w, att_w1, att_w2,
                                          w1f, w2f, gwf, aw1f, aw2t);
    hipMemsetAsync(m0, 0, 3*2048*sizeof(float), stream);   // zero m0,m1,m2 each call

    // ODE: 5 double-RK4-steps (fp32 carry via LDS Z0F). Chain:
    // x -> WSB -> Z -> WSB -> Z -> WSB  (x_evolved in WSB; last fuses m0 sums)
    dim3 gOde(Ln/NTD, Bn);
    ode_rk4_2step<<<gOde, 256, 0, stream>>>(x,   WSB, w1f, c1b, w2f, c2b, damp, nullptr);
    ode_rk4_2step<<<gOde, 256, 0, stream>>>(WSB, Z,   w1f, c1b, w2f, c2b, damp, nullptr);
    ode_rk4_2step<<<gOde, 256, 0, stream>>>(Z,   WSB, w1f, c1b, w2f, c2b, damp, nullptr);
    ode_rk4_2step<<<gOde, 256, 0, stream>>>(WSB, Z,   w1f, c1b, w2f, c2b, damp, nullptr);
    ode_rk4_2step<<<gOde, 256, 0, stream>>>(Z,   WSB, w1f, c1b, w2f, c2b, damp, m0);

    // stage 2: wavelet levels. approx chain: WSB -> Z -> out0 -> (dropped)
    dim3 gFil(Ln/256, Bn*Cn);
    const float* appr_in[3]  = {WSB, Z, out};
    float*       appr_out[3] = {Z, out, nullptr};
    float*       msum[3]     = {m1, m2, nullptr};
    float*       muse[3]     = {m0, m1, m2};
    for (int lvl = 0; lvl < 3; ++lvl) {
        dywan_kernel<<<1, 256, 0, stream>>>(muse[lvl], stat_w, stat_b, gen1_w, gen1_b,
                                            gen2_w, gen2_b, tail, lvl);
        filter_kernel<<<gFil, 256, 0, stream>>>(appr_in[lvl], appr_out[lvl],
            out + (size_t)(1+lvl)*Nn,
            tail + 1 + lvl*(Bn*FLn),
            tail + 1 + 3*(Bn*FLn) + lvl*(Bn*FLn),
            msum[lvl]);
    }

    // stage 3: reconstruction. cur chain: WSB -> Z -> WSB -> out0 (final)
    dim3 gS3(Ln/TILE3, Bn);
    stage3_kernel<false><<<gS3, 256, 0, stream>>>(WSB, out + (size_t)3*Nn, Z,
        gwf + 2*12288, gate_b + 2*64, nullptr, nullptr, nullptr, nullptr);
    stage3_kernel<true><<<gS3, 256, 0, stream>>>(Z, out + (size_t)2*Nn, WSB,
        gwf + 1*12288, gate_b + 1*64, aw1f + 1024, att_b1 + 16, aw2t + 1024, att_b2 + 64);
    stage3_kernel<true><<<gS3, 256, 0, stream>>>(WSB, out + (size_t)1*Nn, out,
        gwf, gate_b, aw1f, att_b1, aw2t, att_b2);
}